// Round 5
// baseline (480.065 us; speedup 1.0000x reference)
//
#include <hip/hip_runtime.h>
#include <math.h>

#define HID 64
#define HEADS 4
#define HDIM 16
#define N_MOL 2048
#define N_PROT 4096
#define E_MOL 32768
#define E_PROT 131072
#define BATCH 32
#define N_TOT (N_MOL + N_PROT)
#define E_TOT (E_MOL + E_PROT)

// attention tiling
#define TQA 16         // queries per block
#define TKA 32         // keys per LDS tile
#define KSTA 68        // LDS row stride (words)
#define CH_MOL 4       // key chunks for mol queries
#define CH_PROT 2      // key chunks for prot queries
#define KCHUNK 1024    // keys per block

#define DOT4(a, b) ((a).x*(b).x + (a).y*(b).y + (a).z*(b).z + (a).w*(b).w)

// ---------------------------------------------------------------------------
// Node input linear + batch counts. 4 nodes/block, one wave per node.
__global__ void k_node_lin(const float* __restrict__ mol_x, const float* __restrict__ prot_x,
                           const float* __restrict__ Wm, const float* __restrict__ bm,
                           const float* __restrict__ Wp, const float* __restrict__ bp,
                           const int* __restrict__ mb, const int* __restrict__ pb,
                           float* __restrict__ xm, float* __restrict__ xp,
                           float* __restrict__ cnt) {
    int w = threadIdx.x >> 6, t = threadIdx.x & 63;
    int n = blockIdx.x * 4 + w;
    if (n < N_MOL) {
        const float* xr = mol_x + n * 11;
        float acc = bm[t];
#pragma unroll
        for (int i = 0; i < 11; ++i) acc += xr[i] * Wm[i * HID + t];
        xm[n * HID + t] = acc;
        if (t == 0) unsafeAtomicAdd(&cnt[mb[n] * 2 + 0], 1.f);
    } else {
        int p = n - N_MOL;
        const float* xr = prot_x + p * 15;
        float acc = bp[t];
#pragma unroll
        for (int i = 0; i < 15; ++i) acc += xr[i] * Wp[i * HID + t];
        xp[p * HID + t] = acc;
        if (t == 0) unsafeAtomicAdd(&cnt[pb[p] * 2 + 1], 1.f);
    }
}

// ---------------------------------------------------------------------------
// CSR build: degree count, exclusive scan, fill edge lists.
__global__ void k_deg(const int* __restrict__ mol_ei, const int* __restrict__ prot_ei,
                      int* __restrict__ deg) {
    int e = blockIdx.x * 256 + threadIdx.x;
    if (e < E_MOL) atomicAdd(&deg[mol_ei[E_MOL + e]], 1);
    else atomicAdd(&deg[N_MOL + prot_ei[E_PROT + (e - E_MOL)]], 1);
}

__global__ void k_scan(const int* __restrict__ deg, int* __restrict__ rowptr,
                       int* __restrict__ cursor) {
    __shared__ int waveSums[4];
    int t = threadIdx.x;                    // 256 threads, 24 nodes each
    int base = t * 24;
    int local[24];
    int s = 0;
#pragma unroll
    for (int i = 0; i < 24; ++i) { local[i] = s; s += deg[base + i]; }
    int lane = t & 63, w = t >> 6;
    int pref = s;
#pragma unroll
    for (int off = 1; off < 64; off <<= 1) {
        int v = __shfl_up(pref, off, 64);
        if (lane >= off) pref += v;
    }
    if (lane == 63) waveSums[w] = pref;
    __syncthreads();
    int waveOff = 0;
    for (int i = 0; i < w; ++i) waveOff += waveSums[i];
    int excl = pref - s + waveOff;
#pragma unroll
    for (int i = 0; i < 24; ++i) {
        rowptr[base + i] = excl + local[i];
        cursor[base + i] = excl + local[i];
    }
    if (t == 255) rowptr[N_TOT] = excl + s;
}

__global__ void k_fill(const int* __restrict__ mol_ei, const int* __restrict__ prot_ei,
                       int* __restrict__ cursor, int* __restrict__ eidx) {
    int e = blockIdx.x * 256 + threadIdx.x;
    int node;
    if (e < E_MOL) node = mol_ei[E_MOL + e];
    else node = N_MOL + prot_ei[E_PROT + (e - E_MOL)];
    int pos = atomicAdd(&cursor[node], 1);
    eidx[pos] = e;     // global edge id (prot offset by E_MOL)
}

// ---------------------------------------------------------------------------
// Fused GINE layer: CSR gather (pairwise-unrolled, no atomics) + node MLP.
// Last layer (doProj) also emits this row's 3 QKV projections.
// 4 nodes per 256-thread block, one wave per node; LDS slices are per-wave
// so no block barriers are needed.
__global__ void k_gine(const float* __restrict__ xin_m, const float* __restrict__ xin_p,
                       float* __restrict__ xout_m, float* __restrict__ xout_p,
                       const float* __restrict__ mol_ea, const float* __restrict__ prot_ea,
                       const int* __restrict__ mol_ei, const int* __restrict__ prot_ei,
                       const float* __restrict__ Wem, const float* __restrict__ bem,
                       const float* __restrict__ Wep, const float* __restrict__ bep,
                       const float* __restrict__ W1m, const float* __restrict__ b1m,
                       const float* __restrict__ W2m, const float* __restrict__ b2m,
                       const float* __restrict__ W1p, const float* __restrict__ b1p,
                       const float* __restrict__ W2p, const float* __restrict__ b2p,
                       const int* __restrict__ rowptr, const int* __restrict__ eidx,
                       int doProj,
                       const float* __restrict__ mpW, const float* __restrict__ mpb,
                       const float* __restrict__ pmW, const float* __restrict__ pmb,
                       float* __restrict__ Qm, float* __restrict__ Kp, float* __restrict__ Vp,
                       float* __restrict__ Qp, float* __restrict__ Km, float* __restrict__ Vm) {
    __shared__ float h0[4][HID];
    __shared__ float h1[4][HID];
    int w = threadIdx.x >> 6, t = threadIdx.x & 63;
    int nb = blockIdx.x * 4 + w;
    bool isMol = nb < N_MOL;
    const float* x = isMol ? xin_m : xin_p;
    float* xo = isMol ? xout_m : xout_p;
    int n = isMol ? nb : nb - N_MOL;
    const float* We = isMol ? Wem : Wep;
    float bt = isMol ? bem[t] : bep[t];
    const float* ea_base = isMol ? mol_ea : prot_ea;
    const int* srcarr = isMol ? mol_ei : prot_ei;
    int ebias = isMol ? 0 : E_MOL;
    float wcol[10];
#pragma unroll
    for (int i = 0; i < 10; ++i) wcol[i] = We[i * HID + t];
    float agg = 0.f;
    int beg = rowptr[nb], end = rowptr[nb + 1];
    int j = beg;
    // pairwise: two independent gather chains in flight
    for (; j + 1 < end; j += 2) {
        int e0 = eidx[j] - ebias;
        int e1 = eidx[j + 1] - ebias;
        int s0 = srcarr[e0];
        int s1 = srcarr[e1];
        const float2* p0 = (const float2*)(ea_base + (size_t)e0 * 10);
        const float2* p1 = (const float2*)(ea_base + (size_t)e1 * 10);
        float2 a0 = p0[0], a1 = p0[1], a2 = p0[2], a3 = p0[3], a4 = p0[4];
        float2 c0 = p1[0], c1 = p1[1], c2 = p1[2], c3 = p1[3], c4 = p1[4];
        float xs0 = x[s0 * HID + t];
        float xs1 = x[s1 * HID + t];
        float m0 = bt, m1 = bt;
        m0 = fmaf(a0.x, wcol[0], m0); m0 = fmaf(a0.y, wcol[1], m0);
        m0 = fmaf(a1.x, wcol[2], m0); m0 = fmaf(a1.y, wcol[3], m0);
        m0 = fmaf(a2.x, wcol[4], m0); m0 = fmaf(a2.y, wcol[5], m0);
        m0 = fmaf(a3.x, wcol[6], m0); m0 = fmaf(a3.y, wcol[7], m0);
        m0 = fmaf(a4.x, wcol[8], m0); m0 = fmaf(a4.y, wcol[9], m0);
        m1 = fmaf(c0.x, wcol[0], m1); m1 = fmaf(c0.y, wcol[1], m1);
        m1 = fmaf(c1.x, wcol[2], m1); m1 = fmaf(c1.y, wcol[3], m1);
        m1 = fmaf(c2.x, wcol[4], m1); m1 = fmaf(c2.y, wcol[5], m1);
        m1 = fmaf(c3.x, wcol[6], m1); m1 = fmaf(c3.y, wcol[7], m1);
        m1 = fmaf(c4.x, wcol[8], m1); m1 = fmaf(c4.y, wcol[9], m1);
        agg += fmaxf(m0 + xs0, 0.f) + fmaxf(m1 + xs1, 0.f);
    }
    if (j < end) {
        int e0 = eidx[j] - ebias;
        int s0 = srcarr[e0];
        const float2* p0 = (const float2*)(ea_base + (size_t)e0 * 10);
        float2 a0 = p0[0], a1 = p0[1], a2 = p0[2], a3 = p0[3], a4 = p0[4];
        float xs0 = x[s0 * HID + t];
        float m0 = bt;
        m0 = fmaf(a0.x, wcol[0], m0); m0 = fmaf(a0.y, wcol[1], m0);
        m0 = fmaf(a1.x, wcol[2], m0); m0 = fmaf(a1.y, wcol[3], m0);
        m0 = fmaf(a2.x, wcol[4], m0); m0 = fmaf(a2.y, wcol[5], m0);
        m0 = fmaf(a3.x, wcol[6], m0); m0 = fmaf(a3.y, wcol[7], m0);
        m0 = fmaf(a4.x, wcol[8], m0); m0 = fmaf(a4.y, wcol[9], m0);
        agg += fmaxf(m0 + xs0, 0.f);
    }
    h0[w][t] = x[n * HID + t] + agg;           // per-wave slice: no barrier
    const float* W1 = isMol ? W1m : W1p;
    const float* W2 = isMol ? W2m : W2p;
    float acc = isMol ? b1m[t] : b1p[t];
    const float4* h0v = (const float4*)h0[w];
#pragma unroll
    for (int k = 0; k < 16; ++k) {
        float4 hv = h0v[k];
        acc = fmaf(hv.x, W1[(4 * k + 0) * HID + t], acc);
        acc = fmaf(hv.y, W1[(4 * k + 1) * HID + t], acc);
        acc = fmaf(hv.z, W1[(4 * k + 2) * HID + t], acc);
        acc = fmaf(hv.w, W1[(4 * k + 3) * HID + t], acc);
    }
    h1[w][t] = fmaxf(acc, 0.f);
    float acc2 = isMol ? b2m[t] : b2p[t];
    const float4* h1v = (const float4*)h1[w];
#pragma unroll
    for (int k = 0; k < 16; ++k) {
        float4 hv = h1v[k];
        acc2 = fmaf(hv.x, W2[(4 * k + 0) * HID + t], acc2);
        acc2 = fmaf(hv.y, W2[(4 * k + 1) * HID + t], acc2);
        acc2 = fmaf(hv.z, W2[(4 * k + 2) * HID + t], acc2);
        acc2 = fmaf(hv.w, W2[(4 * k + 3) * HID + t], acc2);
    }
    float xv = fmaxf(acc2, 0.f);
    xo[n * HID + t] = xv;

    if (doProj) {
        // row-local QKV projections fused into the last layer.
        // mol rows feed Qm (mp.Q), Km (pm.K), Vm (pm.V); prot rows feed
        // Qp (pm.Q), Kp (mp.K), Vp (mp.V).
        h0[w][t] = xv;                         // per-wave slice reuse
        const float *WQ, *bQ, *WK, *bK, *WV, *bV;
        float *dQ, *dK, *dV;
        if (isMol) { WQ = mpW;        bQ = mpb;       WK = pmW + 4096; bK = pmb + 64;
                     WV = pmW + 8192; bV = pmb + 128; dQ = Qm; dK = Km; dV = Vm; }
        else       { WQ = pmW;        bQ = pmb;       WK = mpW + 4096; bK = mpb + 64;
                     WV = mpW + 8192; bV = mpb + 128; dQ = Qp; dK = Kp; dV = Vp; }
        float aQ = bQ[t], aK = bK[t], aV = bV[t];
        const float4* xr4 = (const float4*)h0[w];
#pragma unroll
        for (int k = 0; k < 16; ++k) {
            float4 hv = xr4[k];
            aQ = fmaf(hv.x, WQ[(4 * k + 0) * HID + t], aQ);
            aQ = fmaf(hv.y, WQ[(4 * k + 1) * HID + t], aQ);
            aQ = fmaf(hv.z, WQ[(4 * k + 2) * HID + t], aQ);
            aQ = fmaf(hv.w, WQ[(4 * k + 3) * HID + t], aQ);
            aK = fmaf(hv.x, WK[(4 * k + 0) * HID + t], aK);
            aK = fmaf(hv.y, WK[(4 * k + 1) * HID + t], aK);
            aK = fmaf(hv.z, WK[(4 * k + 2) * HID + t], aK);
            aK = fmaf(hv.w, WK[(4 * k + 3) * HID + t], aK);
            aV = fmaf(hv.x, WV[(4 * k + 0) * HID + t], aV);
            aV = fmaf(hv.y, WV[(4 * k + 1) * HID + t], aV);
            aV = fmaf(hv.z, WV[(4 * k + 2) * HID + t], aV);
            aV = fmaf(hv.w, WV[(4 * k + 3) * HID + t], aV);
        }
        dQ[n * HID + t] = aQ;
        dK[n * HID + t] = aK;
        dV[n * HID + t] = aV;
    }
}

// ---------------------------------------------------------------------------
__device__ inline void upd4(float4& A, const float4 v0, const float4 v1,
                            float p0, float p1, float al) {
    A.x = fmaf(p1, v1.x, fmaf(p0, v0.x, A.x * al));
    A.y = fmaf(p1, v1.y, fmaf(p0, v0.y, A.y * al));
    A.z = fmaf(p1, v1.z, fmaf(p0, v0.z, A.z * al));
    A.w = fmaf(p1, v1.w, fmaf(p0, v0.w, A.w * al));
}

__device__ inline void merge4(float4& A, const float4 B, float c1, float c2) {
    A.x = A.x * c1 + B.x * c2;
    A.y = A.y * c1 + B.y * c2;
    A.z = A.z * c1 + B.z * c2;
    A.w = A.w * c1 + B.w * c2;
}

__device__ inline float4 shfl4(const float4 a, int off) {
    float4 r;
    r.x = __shfl_xor(a.x, off, 64); r.y = __shfl_xor(a.y, off, 64);
    r.z = __shfl_xor(a.z, off, 64); r.w = __shfl_xor(a.w, off, 64);
    return r;
}

// ---------------------------------------------------------------------------
// Tiled cross attention, Q_LOCAL=4, double-buffered LDS (one barrier/tile;
// next tile's global loads in flight during compute).
__global__ __launch_bounds__(256) void k_attn(
    const float* __restrict__ Qm, const float* __restrict__ Kp, const float* __restrict__ Vp,
    const float* __restrict__ Qp, const float* __restrict__ Km, const float* __restrict__ Vm,
    float* __restrict__ part_m, float* __restrict__ part_p) {
    __shared__ float Kl[2][TKA * KSTA];
    __shared__ float Vl[2][TKA * KSTA];

    int t = threadIdx.x;
    const float *Q, *K, *V;
    float* part;
    int q0, chunk, CH;
    {
        int b = blockIdx.x;
        const int MOLB = (N_MOL / TQA) * CH_MOL;   // 512
        if (b < MOLB) {
            chunk = b & 3; q0 = (b >> 2) * TQA; CH = CH_MOL;
            Q = Qm; K = Kp; V = Vp; part = part_m;
        } else {
            b -= MOLB;
            chunk = b & 1; q0 = (b >> 1) * TQA; CH = CH_PROT;
            Q = Qp; K = Km; V = Vm; part = part_p;
        }
    }
    int kbeg = chunk * KCHUNK;

    int sub = t & 15, h = (t >> 4) & 3, qg = t >> 6;
    int r0 = t >> 4;                 // staging row 0..15 (and r0+16)
    int c0 = (t & 15) << 2;          // staging col (words)

    float4 q4[4][4];
#pragma unroll
    for (int qq = 0; qq < 4; ++qq) {
        const float4* Qr = (const float4*)(Q + (q0 + qg * 4 + qq) * HID + h * HDIM);
#pragma unroll
        for (int j = 0; j < 4; ++j) {
            float4 v = Qr[j];
            v.x *= 0.25f; v.y *= 0.25f; v.z *= 0.25f; v.w *= 0.25f;   // 1/sqrt(16)
            q4[qq][j] = v;
        }
    }

    float mreg[4], lreg[4];
    float4 A[4][4];
#pragma unroll
    for (int qq = 0; qq < 4; ++qq) {
        mreg[qq] = -INFINITY; lreg[qq] = 0.f;
#pragma unroll
        for (int j = 0; j < 4; ++j) A[qq][j] = (float4){0.f, 0.f, 0.f, 0.f};
    }

    // prologue: stage tile 0 into buffer 0
    {
        const float4* Kg = (const float4*)(K + kbeg * HID);
        const float4* Vg = (const float4*)(V + kbeg * HID);
        float4 ka = Kg[t], kb = Kg[t + 256];
        float4 va = Vg[t], vb = Vg[t + 256];
        *(float4*)&Kl[0][r0 * KSTA + c0] = ka;
        *(float4*)&Kl[0][(r0 + 16) * KSTA + c0] = kb;
        *(float4*)&Vl[0][r0 * KSTA + c0] = va;
        *(float4*)&Vl[0][(r0 + 16) * KSTA + c0] = vb;
    }
    __syncthreads();

    const int NT = KCHUNK / TKA;     // 32 tiles
    for (int tile = 0; tile < NT; ++tile) {
        int cur = tile & 1;
        float4 ka, kb, va, vb;
        bool more = (tile + 1) < NT;
        if (more) {
            const float4* Kg = (const float4*)(K + (kbeg + (tile + 1) * TKA) * HID);
            const float4* Vg = (const float4*)(V + (kbeg + (tile + 1) * TKA) * HID);
            ka = Kg[t]; kb = Kg[t + 256];
            va = Vg[t]; vb = Vg[t + 256];
        }

        const float4* Kr0 = (const float4*)&Kl[cur][sub * KSTA + h * HDIM];
        const float4* Kr1 = (const float4*)&Kl[cur][(sub + 16) * KSTA + h * HDIM];
        float4 x0 = Kr0[0], x1 = Kr0[1], x2 = Kr0[2], x3 = Kr0[3];
        float4 y0 = Kr1[0], y1 = Kr1[1], y2 = Kr1[2], y3 = Kr1[3];

        float s0[4], s1[4];
#pragma unroll
        for (int qq = 0; qq < 4; ++qq) {
            s0[qq] = DOT4(x0, q4[qq][0]) + DOT4(x1, q4[qq][1]) + DOT4(x2, q4[qq][2]) + DOT4(x3, q4[qq][3]);
            s1[qq] = DOT4(y0, q4[qq][0]) + DOT4(y1, q4[qq][1]) + DOT4(y2, q4[qq][2]) + DOT4(y3, q4[qq][3]);
        }

        const float4* Vr0 = (const float4*)&Vl[cur][sub * KSTA + h * HDIM];
        const float4* Vr1 = (const float4*)&Vl[cur][(sub + 16) * KSTA + h * HDIM];
        float4 v00 = Vr0[0], v01 = Vr0[1], v02 = Vr0[2], v03 = Vr0[3];
        float4 v10 = Vr1[0], v11 = Vr1[1], v12 = Vr1[2], v13 = Vr1[3];

#pragma unroll
        for (int qq = 0; qq < 4; ++qq) {
            float mn = fmaxf(mreg[qq], fmaxf(s0[qq], s1[qq]));
            float al = __expf(mreg[qq] - mn);
            float p0 = __expf(s0[qq] - mn);
            float p1 = __expf(s1[qq] - mn);
            lreg[qq] = lreg[qq] * al + p0 + p1;
            upd4(A[qq][0], v00, v10, p0, p1, al);
            upd4(A[qq][1], v01, v11, p0, p1, al);
            upd4(A[qq][2], v02, v12, p0, p1, al);
            upd4(A[qq][3], v03, v13, p0, p1, al);
            mreg[qq] = mn;
        }

        if (more) {
            int nxt = cur ^ 1;
            *(float4*)&Kl[nxt][r0 * KSTA + c0] = ka;
            *(float4*)&Kl[nxt][(r0 + 16) * KSTA + c0] = kb;
            *(float4*)&Vl[nxt][r0 * KSTA + c0] = va;
            *(float4*)&Vl[nxt][(r0 + 16) * KSTA + c0] = vb;
        }
        __syncthreads();
    }

    // merge 16 partial states across sub lanes (lane bits 0..3)
#pragma unroll
    for (int off = 1; off < 16; off <<= 1) {
#pragma unroll
        for (int qq = 0; qq < 4; ++qq) {
            float m2 = __shfl_xor(mreg[qq], off, 64);
            float l2 = __shfl_xor(lreg[qq], off, 64);
            float4 B0 = shfl4(A[qq][0], off), B1 = shfl4(A[qq][1], off);
            float4 B2 = shfl4(A[qq][2], off), B3 = shfl4(A[qq][3], off);
            float mn = fmaxf(mreg[qq], m2);
            float c1 = __expf(mreg[qq] - mn), c2 = __expf(m2 - mn);
            lreg[qq] = lreg[qq] * c1 + l2 * c2;
            merge4(A[qq][0], B0, c1, c2); merge4(A[qq][1], B1, c1, c2);
            merge4(A[qq][2], B2, c1, c2); merge4(A[qq][3], B3, c1, c2);
            mreg[qq] = mn;
        }
    }

    if (sub == 0) {
#pragma unroll
        for (int qq = 0; qq < 4; ++qq) {
            int qi = q0 + qg * 4 + qq;
            float* pp = part + (size_t)((qi * HEADS + h) * CH + chunk) * 20;
            pp[0] = mreg[qq]; pp[1] = lreg[qq];
            *(float4*)&pp[4] = A[qq][0]; *(float4*)&pp[8] = A[qq][1];
            *(float4*)&pp[12] = A[qq][2]; *(float4*)&pp[16] = A[qq][3];
        }
    }
}

// ---------------------------------------------------------------------------
// Merge chunk partials per (q,h), normalize, add residual, pool directly
// (H never materialized). Thread <-> (q,h); 16 atomics each.
__global__ void k_attn_merge(const float* __restrict__ part_m, const float* __restrict__ part_p,
                             const float* __restrict__ xm, const float* __restrict__ xp,
                             const int* __restrict__ mb, const int* __restrict__ pb,
                             float* __restrict__ pool) {
    int gi = blockIdx.x * 256 + threadIdx.x;
    const float *part, *X;
    int CH, poff, b;
    int q, h;
    if (gi < N_MOL * HEADS) {
        part = part_m; X = xm; CH = CH_MOL; poff = 0;
        q = gi >> 2; h = gi & 3; b = mb[q];
    } else {
        gi -= N_MOL * HEADS;
        part = part_p; X = xp; CH = CH_PROT; poff = 64;
        q = gi >> 2; h = gi & 3; b = pb[q];
    }
    const float* p0 = part + (size_t)(q * HEADS + h) * CH * 20;
    float mmax = -INFINITY;
    for (int c = 0; c < CH; ++c) mmax = fmaxf(mmax, p0[c * 20]);
    float lsum = 0.f, wgt[4];
    for (int c = 0; c < CH; ++c) {
        wgt[c] = __expf(p0[c * 20] - mmax);
        lsum += p0[c * 20 + 1] * wgt[c];
    }
    float inv = 1.f / lsum;
    const float4* Xr = (const float4*)(X + q * HID + h * HDIM);
    float* pdst = pool + b * 128 + poff + h * HDIM;
#pragma unroll
    for (int j = 0; j < 4; ++j) {
        float4 o = Xr[j];
        for (int c = 0; c < CH; ++c) {
            const float4 Av = *(const float4*)(p0 + c * 20 + 4 + 4 * j);
            float wc = wgt[c] * inv;
            o.x += Av.x * wc; o.y += Av.y * wc; o.z += Av.z * wc; o.w += Av.w * wc;
        }
        unsafeAtomicAdd(&pdst[4 * j + 0], o.x);
        unsafeAtomicAdd(&pdst[4 * j + 1], o.y);
        unsafeAtomicAdd(&pdst[4 * j + 2], o.z);
        unsafeAtomicAdd(&pdst[4 * j + 3], o.w);
    }
}

// ---------------------------------------------------------------------------
// Head: z = [mean_mol | mean_prot]; relu(z@fc1+b1)@fc2+b2 -> sigmoid.
__global__ void k_final(const float* __restrict__ pool, const float* __restrict__ cnt,
                        const float* __restrict__ fc1W, const float* __restrict__ fc1b,
                        const float* __restrict__ fc2W, const float* __restrict__ fc2b,
                        float* __restrict__ out) {
    __shared__ float z[128];
    int b = blockIdx.x, t = threadIdx.x;
    float cm = fmaxf(cnt[b * 2 + 0], 1.f), cp = fmaxf(cnt[b * 2 + 1], 1.f);
    z[t] = pool[b * 128 + t] / cm;
    z[64 + t] = pool[b * 128 + 64 + t] / cp;
    __syncthreads();
    float acc = fc1b[t];
    const float4* zv = (const float4*)z;
#pragma unroll
    for (int k = 0; k < 32; ++k) {
        float4 hv = zv[k];
        acc = fmaf(hv.x, fc1W[(4 * k + 0) * 64 + t], acc);
        acc = fmaf(hv.y, fc1W[(4 * k + 1) * 64 + t], acc);
        acc = fmaf(hv.z, fc1W[(4 * k + 2) * 64 + t], acc);
        acc = fmaf(hv.w, fc1W[(4 * k + 3) * 64 + t], acc);
    }
    float hv = fmaxf(acc, 0.f);
    float prod = hv * fc2W[t];
#pragma unroll
    for (int off = 32; off > 0; off >>= 1) prod += __shfl_xor(prod, off, 64);
    if (t == 0) out[b] = 1.f / (1.f + __expf(-(prod + fc2b[0])));
}

// ---------------------------------------------------------------------------
extern "C" void kernel_launch(void* const* d_in, const int* in_sizes, int n_in,
                              void* d_out, int out_size, void* d_ws, size_t ws_size,
                              hipStream_t stream) {
    const float* mol_x   = (const float*)d_in[0];
    const float* prot_x  = (const float*)d_in[1];
    const float* mol_ea  = (const float*)d_in[2];
    const float* prot_ea = (const float*)d_in[3];
    const int*   mol_ei  = (const int*)d_in[4];
    const int*   prot_ei = (const int*)d_in[5];
    const int*   mol_b   = (const int*)d_in[6];
    const int*   prot_b  = (const int*)d_in[7];
    const float* nlmW = (const float*)d_in[8];
    const float* nlmb = (const float*)d_in[9];
    const float* nlpW = (const float*)d_in[10];
    const float* nlpb = (const float*)d_in[11];
    const float* elmW = (const float*)d_in[12];
    const float* elmb = (const float*)d_in[13];
    const float* elpW = (const float*)d_in[14];
    const float* elpb = (const float*)d_in[15];
    const float* mcW1 = (const float*)d_in[16];
    const float* mcb1 = (const float*)d_in[17];
    const float* mcW2 = (const float*)d_in[18];
    const float* mcb2 = (const float*)d_in[19];
    const float* pcW1 = (const float*)d_in[20];
    const float* pcb1 = (const float*)d_in[21];
    const float* pcW2 = (const float*)d_in[22];
    const float* pcb2 = (const float*)d_in[23];
    const float* mpW  = (const float*)d_in[24];
    const float* mpb  = (const float*)d_in[25];
    const float* pmW  = (const float*)d_in[26];
    const float* pmb  = (const float*)d_in[27];
    const float* fc1W = (const float*)d_in[28];
    const float* fc1b = (const float*)d_in[29];
    const float* fc2W = (const float*)d_in[30];
    const float* fc2b = (const float*)d_in[31];

    float* ws    = (float*)d_ws;
    float* xa_m  = ws;                  // 131072
    float* xa_p  = xa_m + 131072;       // 262144
    float* xb_m  = xa_p + 262144;       // 131072
    float* xb_p  = xb_m + 131072;       // 262144
    float* Qm    = xb_p + 262144;       // 131072
    float* Kp    = Qm + 131072;         // 262144
    float* Vp    = Kp + 262144;         // 262144
    float* Qp    = Vp + 262144;         // 262144
    float* Km    = Qp + 262144;         // 131072
    float* Vm    = Km + 131072;         // 131072
    float* partm = Vm + 131072;         // 2048*4*4*20 = 655360
    float* partp = partm + 655360;      // 4096*4*2*20 = 655360
    float* pool  = partp + 655360;      // 4096   } one
    float* cnt   = pool + 4096;         // 64     } contiguous
    int* deg     = (int*)(cnt + 64);    // 6144   } memset
    int* rowptr  = deg + N_TOT;         // 6145
    int* cursor  = rowptr + N_TOT + 1;  // 6144
    int* eidx    = cursor + N_TOT;      // 163840

    hipMemsetAsync(pool, 0, (size_t)(4096 + 64 + N_TOT) * 4, stream);

    k_node_lin<<<N_TOT / 4, 256, 0, stream>>>(mol_x, prot_x, nlmW, nlmb, nlpW, nlpb,
                                              mol_b, prot_b, xa_m, xa_p, cnt);
    k_deg<<<E_TOT / 256, 256, 0, stream>>>(mol_ei, prot_ei, deg);
    k_scan<<<1, 256, 0, stream>>>(deg, rowptr, cursor);
    k_fill<<<E_TOT / 256, 256, 0, stream>>>(mol_ei, prot_ei, cursor, eidx);

    // 3 GINE layers, ping-pong xa <-> xb; layer 3 fuses the QKV projections
    k_gine<<<N_TOT / 4, 256, 0, stream>>>(xa_m, xa_p, xb_m, xb_p, mol_ea, prot_ea, mol_ei, prot_ei,
        elmW, elmb, elpW, elpb,
        mcW1, mcb1, mcW2, mcb2, pcW1, pcb1, pcW2, pcb2, rowptr, eidx,
        0, mpW, mpb, pmW, pmb, Qm, Kp, Vp, Qp, Km, Vm);
    k_gine<<<N_TOT / 4, 256, 0, stream>>>(xb_m, xb_p, xa_m, xa_p, mol_ea, prot_ea, mol_ei, prot_ei,
        elmW, elmb, elpW, elpb,
        mcW1 + 4096, mcb1 + 64, mcW2 + 4096, mcb2 + 64,
        pcW1 + 4096, pcb1 + 64, pcW2 + 4096, pcb2 + 64, rowptr, eidx,
        0, mpW, mpb, pmW, pmb, Qm, Kp, Vp, Qp, Km, Vm);
    k_gine<<<N_TOT / 4, 256, 0, stream>>>(xa_m, xa_p, xb_m, xb_p, mol_ea, prot_ea, mol_ei, prot_ei,
        elmW, elmb, elpW, elpb,
        mcW1 + 8192, mcb1 + 128, mcW2 + 8192, mcb2 + 128,
        pcW1 + 8192, pcb1 + 128, pcW2 + 8192, pcb2 + 128, rowptr, eidx,
        1, mpW, mpb, pmW, pmb, Qm, Kp, Vp, Qp, Km, Vm);

    k_attn<<<(N_MOL / TQA) * CH_MOL + (N_PROT / TQA) * CH_PROT, 256, 0, stream>>>(
        Qm, Kp, Vp, Qp, Km, Vm, partm, partp);
    k_attn_merge<<<(N_MOL + N_PROT) * HEADS / 256, 256, 0, stream>>>(
        partm, partp, xb_m, xb_p, mol_b, prot_b, pool);

    k_final<<<BATCH, 64, 0, stream>>>(pool, cnt, fc1W, fc1b, fc2W, fc2b, (float*)d_out);
}

// Round 6
// 401.971 us; speedup vs baseline: 1.1943x; 1.1943x over previous
//
#include <hip/hip_runtime.h>
#include <math.h>

#define HID 64
#define HEADS 4
#define HDIM 16
#define N_MOL 2048
#define N_PROT 4096
#define E_MOL 32768
#define E_PROT 131072
#define BATCH 32
#define N_TOT (N_MOL + N_PROT)
#define E_TOT (E_MOL + E_PROT)

// attention tiling
#define TQA 16         // queries per block
#define TKA 32         // keys per LDS tile
#define KSTA 68        // LDS row stride (words)
#define CH_MOL 4       // key chunks for mol queries
#define CH_PROT 2      // key chunks for prot queries
#define KCHUNK 1024    // keys per block

#define DOT4(a, b) ((a).x*(b).x + (a).y*(b).y + (a).z*(b).z + (a).w*(b).w)

// ---------------------------------------------------------------------------
// Node input linear. 4 nodes/block, one wave per node.
__global__ void k_node_lin(const float* __restrict__ mol_x, const float* __restrict__ prot_x,
                           const float* __restrict__ Wm, const float* __restrict__ bm,
                           const float* __restrict__ Wp, const float* __restrict__ bp,
                           float* __restrict__ xm, float* __restrict__ xp) {
    int w = threadIdx.x >> 6, t = threadIdx.x & 63;
    int n = blockIdx.x * 4 + w;
    if (n < N_MOL) {
        const float* xr = mol_x + n * 11;
        float acc = bm[t];
#pragma unroll
        for (int i = 0; i < 11; ++i) acc += xr[i] * Wm[i * HID + t];
        xm[n * HID + t] = acc;
    } else {
        int p = n - N_MOL;
        const float* xr = prot_x + p * 15;
        float acc = bp[t];
#pragma unroll
        for (int i = 0; i < 15; ++i) acc += xr[i] * Wp[i * HID + t];
        xp[p * HID + t] = acc;
    }
}

// ---------------------------------------------------------------------------
// CSR build: degree count, exclusive scan, fill edge lists.
__global__ void k_deg(const int* __restrict__ mol_ei, const int* __restrict__ prot_ei,
                      int* __restrict__ deg) {
    int e = blockIdx.x * 256 + threadIdx.x;
    if (e < E_MOL) atomicAdd(&deg[mol_ei[E_MOL + e]], 1);
    else atomicAdd(&deg[N_MOL + prot_ei[E_PROT + (e - E_MOL)]], 1);
}

__global__ void k_scan(const int* __restrict__ deg, int* __restrict__ rowptr,
                       int* __restrict__ cursor) {
    __shared__ int waveSums[4];
    int t = threadIdx.x;                    // 256 threads, 24 nodes each
    int base = t * 24;
    int local[24];
    int s = 0;
#pragma unroll
    for (int i = 0; i < 24; ++i) { local[i] = s; s += deg[base + i]; }
    int lane = t & 63, w = t >> 6;
    int pref = s;
#pragma unroll
    for (int off = 1; off < 64; off <<= 1) {
        int v = __shfl_up(pref, off, 64);
        if (lane >= off) pref += v;
    }
    if (lane == 63) waveSums[w] = pref;
    __syncthreads();
    int waveOff = 0;
    for (int i = 0; i < w; ++i) waveOff += waveSums[i];
    int excl = pref - s + waveOff;
#pragma unroll
    for (int i = 0; i < 24; ++i) {
        rowptr[base + i] = excl + local[i];
        cursor[base + i] = excl + local[i];
    }
    if (t == 255) rowptr[N_TOT] = excl + s;
}

__global__ void k_fill(const int* __restrict__ mol_ei, const int* __restrict__ prot_ei,
                       int* __restrict__ cursor, int* __restrict__ eidx) {
    int e = blockIdx.x * 256 + threadIdx.x;
    int node;
    if (e < E_MOL) node = mol_ei[E_MOL + e];
    else node = N_MOL + prot_ei[E_PROT + (e - E_MOL)];
    int pos = atomicAdd(&cursor[node], 1);
    eidx[pos] = e;     // global edge id (prot offset by E_MOL)
}

// ---------------------------------------------------------------------------
// Fused GINE layer: CSR gather (pairwise-unrolled, no atomics) + node MLP.
// 4 nodes per 256-thread block, one wave per node; LDS slices are per-wave.
__global__ void k_gine(const float* __restrict__ xin_m, const float* __restrict__ xin_p,
                       float* __restrict__ xout_m, float* __restrict__ xout_p,
                       const float* __restrict__ mol_ea, const float* __restrict__ prot_ea,
                       const int* __restrict__ mol_ei, const int* __restrict__ prot_ei,
                       const float* __restrict__ Wem, const float* __restrict__ bem,
                       const float* __restrict__ Wep, const float* __restrict__ bep,
                       const float* __restrict__ W1m, const float* __restrict__ b1m,
                       const float* __restrict__ W2m, const float* __restrict__ b2m,
                       const float* __restrict__ W1p, const float* __restrict__ b1p,
                       const float* __restrict__ W2p, const float* __restrict__ b2p,
                       const int* __restrict__ rowptr, const int* __restrict__ eidx) {
    __shared__ float h0[4][HID];
    __shared__ float h1[4][HID];
    int w = threadIdx.x >> 6, t = threadIdx.x & 63;
    int nb = blockIdx.x * 4 + w;
    bool isMol = nb < N_MOL;
    const float* x = isMol ? xin_m : xin_p;
    float* xo = isMol ? xout_m : xout_p;
    int n = isMol ? nb : nb - N_MOL;
    const float* We = isMol ? Wem : Wep;
    float bt = isMol ? bem[t] : bep[t];
    const float* ea_base = isMol ? mol_ea : prot_ea;
    const int* srcarr = isMol ? mol_ei : prot_ei;
    int ebias = isMol ? 0 : E_MOL;
    float wcol[10];
#pragma unroll
    for (int i = 0; i < 10; ++i) wcol[i] = We[i * HID + t];
    float agg = 0.f;
    int beg = rowptr[nb], end = rowptr[nb + 1];
    int j = beg;
    for (; j + 1 < end; j += 2) {
        int e0 = eidx[j] - ebias;
        int e1 = eidx[j + 1] - ebias;
        int s0 = srcarr[e0];
        int s1 = srcarr[e1];
        const float2* p0 = (const float2*)(ea_base + (size_t)e0 * 10);
        const float2* p1 = (const float2*)(ea_base + (size_t)e1 * 10);
        float2 a0 = p0[0], a1 = p0[1], a2 = p0[2], a3 = p0[3], a4 = p0[4];
        float2 c0 = p1[0], c1 = p1[1], c2 = p1[2], c3 = p1[3], c4 = p1[4];
        float xs0 = x[s0 * HID + t];
        float xs1 = x[s1 * HID + t];
        float m0 = bt, m1 = bt;
        m0 = fmaf(a0.x, wcol[0], m0); m0 = fmaf(a0.y, wcol[1], m0);
        m0 = fmaf(a1.x, wcol[2], m0); m0 = fmaf(a1.y, wcol[3], m0);
        m0 = fmaf(a2.x, wcol[4], m0); m0 = fmaf(a2.y, wcol[5], m0);
        m0 = fmaf(a3.x, wcol[6], m0); m0 = fmaf(a3.y, wcol[7], m0);
        m0 = fmaf(a4.x, wcol[8], m0); m0 = fmaf(a4.y, wcol[9], m0);
        m1 = fmaf(c0.x, wcol[0], m1); m1 = fmaf(c0.y, wcol[1], m1);
        m1 = fmaf(c1.x, wcol[2], m1); m1 = fmaf(c1.y, wcol[3], m1);
        m1 = fmaf(c2.x, wcol[4], m1); m1 = fmaf(c2.y, wcol[5], m1);
        m1 = fmaf(c3.x, wcol[6], m1); m1 = fmaf(c3.y, wcol[7], m1);
        m1 = fmaf(c4.x, wcol[8], m1); m1 = fmaf(c4.y, wcol[9], m1);
        agg += fmaxf(m0 + xs0, 0.f) + fmaxf(m1 + xs1, 0.f);
    }
    if (j < end) {
        int e0 = eidx[j] - ebias;
        int s0 = srcarr[e0];
        const float2* p0 = (const float2*)(ea_base + (size_t)e0 * 10);
        float2 a0 = p0[0], a1 = p0[1], a2 = p0[2], a3 = p0[3], a4 = p0[4];
        float xs0 = x[s0 * HID + t];
        float m0 = bt;
        m0 = fmaf(a0.x, wcol[0], m0); m0 = fmaf(a0.y, wcol[1], m0);
        m0 = fmaf(a1.x, wcol[2], m0); m0 = fmaf(a1.y, wcol[3], m0);
        m0 = fmaf(a2.x, wcol[4], m0); m0 = fmaf(a2.y, wcol[5], m0);
        m0 = fmaf(a3.x, wcol[6], m0); m0 = fmaf(a3.y, wcol[7], m0);
        m0 = fmaf(a4.x, wcol[8], m0); m0 = fmaf(a4.y, wcol[9], m0);
        agg += fmaxf(m0 + xs0, 0.f);
    }
    h0[w][t] = x[n * HID + t] + agg;           // per-wave slice: no barrier
    const float* W1 = isMol ? W1m : W1p;
    const float* W2 = isMol ? W2m : W2p;
    float acc = isMol ? b1m[t] : b1p[t];
    const float4* h0v = (const float4*)h0[w];
#pragma unroll
    for (int k = 0; k < 16; ++k) {
        float4 hv = h0v[k];
        acc = fmaf(hv.x, W1[(4 * k + 0) * HID + t], acc);
        acc = fmaf(hv.y, W1[(4 * k + 1) * HID + t], acc);
        acc = fmaf(hv.z, W1[(4 * k + 2) * HID + t], acc);
        acc = fmaf(hv.w, W1[(4 * k + 3) * HID + t], acc);
    }
    h1[w][t] = fmaxf(acc, 0.f);
    float acc2 = isMol ? b2m[t] : b2p[t];
    const float4* h1v = (const float4*)h1[w];
#pragma unroll
    for (int k = 0; k < 16; ++k) {
        float4 hv = h1v[k];
        acc2 = fmaf(hv.x, W2[(4 * k + 0) * HID + t], acc2);
        acc2 = fmaf(hv.y, W2[(4 * k + 1) * HID + t], acc2);
        acc2 = fmaf(hv.z, W2[(4 * k + 2) * HID + t], acc2);
        acc2 = fmaf(hv.w, W2[(4 * k + 3) * HID + t], acc2);
    }
    xo[n * HID + t] = fmaxf(acc2, 0.f);
}

// ---------------------------------------------------------------------------
// QKV projections: 4 rows per 256-thread block, one wave per row.
__global__ void k_qkv(const float* __restrict__ xm, const float* __restrict__ xp,
                      const float* __restrict__ mpW, const float* __restrict__ mpb,
                      const float* __restrict__ pmW, const float* __restrict__ pmb,
                      float* __restrict__ Qm, float* __restrict__ Kp, float* __restrict__ Vp,
                      float* __restrict__ Qp, float* __restrict__ Km, float* __restrict__ Vm) {
    __shared__ float row[4][HID];
    int w = threadIdx.x >> 6, t = threadIdx.x & 63;
    int b = blockIdx.x * 4 + w;
    const float *src, *W, *bias;
    float* dst;
    int n;
    if (b < 2048)       { n = b;         src = xm; W = mpW;        bias = mpb;       dst = Qm; }
    else if (b < 6144)  { n = b - 2048;  src = xp; W = mpW + 4096; bias = mpb + 64;  dst = Kp; }
    else if (b < 10240) { n = b - 6144;  src = xp; W = mpW + 8192; bias = mpb + 128; dst = Vp; }
    else if (b < 14336) { n = b - 10240; src = xp; W = pmW;        bias = pmb;       dst = Qp; }
    else if (b < 16384) { n = b - 14336; src = xm; W = pmW + 4096; bias = pmb + 64;  dst = Km; }
    else                { n = b - 16384; src = xm; W = pmW + 8192; bias = pmb + 128; dst = Vm; }
    row[w][t] = src[n * HID + t];
    __syncthreads();
    float acc = bias[t];
    const float4* rv = (const float4*)row[w];
#pragma unroll
    for (int k = 0; k < 16; ++k) {
        float4 hv = rv[k];
        acc = fmaf(hv.x, W[(4 * k + 0) * HID + t], acc);
        acc = fmaf(hv.y, W[(4 * k + 1) * HID + t], acc);
        acc = fmaf(hv.z, W[(4 * k + 2) * HID + t], acc);
        acc = fmaf(hv.w, W[(4 * k + 3) * HID + t], acc);
    }
    dst[n * HID + t] = acc;
}

// ---------------------------------------------------------------------------
__device__ inline void upd4(float4& A, const float4 v0, const float4 v1,
                            float p0, float p1, float al) {
    A.x = fmaf(p1, v1.x, fmaf(p0, v0.x, A.x * al));
    A.y = fmaf(p1, v1.y, fmaf(p0, v0.y, A.y * al));
    A.z = fmaf(p1, v1.z, fmaf(p0, v0.z, A.z * al));
    A.w = fmaf(p1, v1.w, fmaf(p0, v0.w, A.w * al));
}

__device__ inline void merge4(float4& A, const float4 B, float c1, float c2) {
    A.x = A.x * c1 + B.x * c2;
    A.y = A.y * c1 + B.y * c2;
    A.z = A.z * c1 + B.z * c2;
    A.w = A.w * c1 + B.w * c2;
}

__device__ inline float4 shfl4(const float4 a, int off) {
    float4 r;
    r.x = __shfl_xor(a.x, off, 64); r.y = __shfl_xor(a.y, off, 64);
    r.z = __shfl_xor(a.z, off, 64); r.w = __shfl_xor(a.w, off, 64);
    return r;
}

// ---------------------------------------------------------------------------
// Tiled cross attention, Q_LOCAL=4, double-buffered LDS, base-2 softmax
// (0.25*log2e folded into q; all exps are single v_exp_f32).
__global__ __launch_bounds__(256) void k_attn(
    const float* __restrict__ Qm, const float* __restrict__ Kp, const float* __restrict__ Vp,
    const float* __restrict__ Qp, const float* __restrict__ Km, const float* __restrict__ Vm,
    float* __restrict__ part_m, float* __restrict__ part_p) {
    __shared__ float Kl[2][TKA * KSTA];
    __shared__ float Vl[2][TKA * KSTA];

    int t = threadIdx.x;
    const float *Q, *K, *V;
    float* part;
    int q0, chunk, CH;
    {
        int b = blockIdx.x;
        const int MOLB = (N_MOL / TQA) * CH_MOL;   // 512
        if (b < MOLB) {
            chunk = b & 3; q0 = (b >> 2) * TQA; CH = CH_MOL;
            Q = Qm; K = Kp; V = Vp; part = part_m;
        } else {
            b -= MOLB;
            chunk = b & 1; q0 = (b >> 1) * TQA; CH = CH_PROT;
            Q = Qp; K = Km; V = Vm; part = part_p;
        }
    }
    int kbeg = chunk * KCHUNK;

    int sub = t & 15, h = (t >> 4) & 3, qg = t >> 6;
    int r0 = t >> 4;                 // staging row 0..15 (and r0+16)
    int c0 = (t & 15) << 2;          // staging col (words)

    const float sc = 0.25f * 1.44269504088896f;   // 1/sqrt(16) * log2(e)
    float4 q4[4][4];
#pragma unroll
    for (int qq = 0; qq < 4; ++qq) {
        const float4* Qr = (const float4*)(Q + (q0 + qg * 4 + qq) * HID + h * HDIM);
#pragma unroll
        for (int j = 0; j < 4; ++j) {
            float4 v = Qr[j];
            v.x *= sc; v.y *= sc; v.z *= sc; v.w *= sc;
            q4[qq][j] = v;
        }
    }

    float mreg[4], lreg[4];
    float4 A[4][4];
#pragma unroll
    for (int qq = 0; qq < 4; ++qq) {
        mreg[qq] = -INFINITY; lreg[qq] = 0.f;
#pragma unroll
        for (int j = 0; j < 4; ++j) A[qq][j] = (float4){0.f, 0.f, 0.f, 0.f};
    }

    // prologue: stage tile 0 into buffer 0
    {
        const float4* Kg = (const float4*)(K + kbeg * HID);
        const float4* Vg = (const float4*)(V + kbeg * HID);
        float4 ka = Kg[t], kb = Kg[t + 256];
        float4 va = Vg[t], vb = Vg[t + 256];
        *(float4*)&Kl[0][r0 * KSTA + c0] = ka;
        *(float4*)&Kl[0][(r0 + 16) * KSTA + c0] = kb;
        *(float4*)&Vl[0][r0 * KSTA + c0] = va;
        *(float4*)&Vl[0][(r0 + 16) * KSTA + c0] = vb;
    }
    __syncthreads();

    const int NT = KCHUNK / TKA;     // 32 tiles
    for (int tile = 0; tile < NT; ++tile) {
        int cur = tile & 1;
        float4 ka, kb, va, vb;
        bool more = (tile + 1) < NT;
        if (more) {
            const float4* Kg = (const float4*)(K + (kbeg + (tile + 1) * TKA) * HID);
            const float4* Vg = (const float4*)(V + (kbeg + (tile + 1) * TKA) * HID);
            ka = Kg[t]; kb = Kg[t + 256];
            va = Vg[t]; vb = Vg[t + 256];
        }

        const float4* Kr0 = (const float4*)&Kl[cur][sub * KSTA + h * HDIM];
        const float4* Kr1 = (const float4*)&Kl[cur][(sub + 16) * KSTA + h * HDIM];
        float4 x0 = Kr0[0], x1 = Kr0[1], x2 = Kr0[2], x3 = Kr0[3];
        float4 y0 = Kr1[0], y1 = Kr1[1], y2 = Kr1[2], y3 = Kr1[3];

        float s0[4], s1[4];
#pragma unroll
        for (int qq = 0; qq < 4; ++qq) {
            s0[qq] = DOT4(x0, q4[qq][0]) + DOT4(x1, q4[qq][1]) + DOT4(x2, q4[qq][2]) + DOT4(x3, q4[qq][3]);
            s1[qq] = DOT4(y0, q4[qq][0]) + DOT4(y1, q4[qq][1]) + DOT4(y2, q4[qq][2]) + DOT4(y3, q4[qq][3]);
        }

        const float4* Vr0 = (const float4*)&Vl[cur][sub * KSTA + h * HDIM];
        const float4* Vr1 = (const float4*)&Vl[cur][(sub + 16) * KSTA + h * HDIM];
        float4 v00 = Vr0[0], v01 = Vr0[1], v02 = Vr0[2], v03 = Vr0[3];
        float4 v10 = Vr1[0], v11 = Vr1[1], v12 = Vr1[2], v13 = Vr1[3];

#pragma unroll
        for (int qq = 0; qq < 4; ++qq) {
            float mn = fmaxf(mreg[qq], fmaxf(s0[qq], s1[qq]));
            float al = exp2f(mreg[qq] - mn);
            float p0 = exp2f(s0[qq] - mn);
            float p1 = exp2f(s1[qq] - mn);
            lreg[qq] = lreg[qq] * al + p0 + p1;
            upd4(A[qq][0], v00, v10, p0, p1, al);
            upd4(A[qq][1], v01, v11, p0, p1, al);
            upd4(A[qq][2], v02, v12, p0, p1, al);
            upd4(A[qq][3], v03, v13, p0, p1, al);
            mreg[qq] = mn;
        }

        if (more) {
            int nxt = cur ^ 1;
            *(float4*)&Kl[nxt][r0 * KSTA + c0] = ka;
            *(float4*)&Kl[nxt][(r0 + 16) * KSTA + c0] = kb;
            *(float4*)&Vl[nxt][r0 * KSTA + c0] = va;
            *(float4*)&Vl[nxt][(r0 + 16) * KSTA + c0] = vb;
        }
        __syncthreads();
    }

    // merge 16 partial states across sub lanes (lane bits 0..3)
#pragma unroll
    for (int off = 1; off < 16; off <<= 1) {
#pragma unroll
        for (int qq = 0; qq < 4; ++qq) {
            float m2 = __shfl_xor(mreg[qq], off, 64);
            float l2 = __shfl_xor(lreg[qq], off, 64);
            float4 B0 = shfl4(A[qq][0], off), B1 = shfl4(A[qq][1], off);
            float4 B2 = shfl4(A[qq][2], off), B3 = shfl4(A[qq][3], off);
            float mn = fmaxf(mreg[qq], m2);
            float c1 = exp2f(mreg[qq] - mn), c2 = exp2f(m2 - mn);
            lreg[qq] = lreg[qq] * c1 + l2 * c2;
            merge4(A[qq][0], B0, c1, c2); merge4(A[qq][1], B1, c1, c2);
            merge4(A[qq][2], B2, c1, c2); merge4(A[qq][3], B3, c1, c2);
            mreg[qq] = mn;
        }
    }

    if (sub == 0) {
#pragma unroll
        for (int qq = 0; qq < 4; ++qq) {
            int qi = q0 + qg * 4 + qq;
            float* pp = part + (size_t)((qi * HEADS + h) * CH + chunk) * 20;
            pp[0] = mreg[qq]; pp[1] = lreg[qq];
            *(float4*)&pp[4] = A[qq][0]; *(float4*)&pp[8] = A[qq][1];
            *(float4*)&pp[12] = A[qq][2]; *(float4*)&pp[16] = A[qq][3];
        }
    }
}

// ---------------------------------------------------------------------------
// Merge chunk partials per (q,h), normalize (base-2 m), add residual, write H.
__global__ void k_attn_merge(const float* __restrict__ part_m, const float* __restrict__ part_p,
                             const float* __restrict__ xm, const float* __restrict__ xp,
                             float* __restrict__ Hm, float* __restrict__ Hp) {
    int gi = blockIdx.x * 256 + threadIdx.x;
    const float *part, *X;
    float* H;
    int CH;
    if (gi < N_MOL * HEADS) { part = part_m; X = xm; H = Hm; CH = CH_MOL; }
    else { gi -= N_MOL * HEADS; part = part_p; X = xp; H = Hp; CH = CH_PROT; }
    int q = gi >> 2, h = gi & 3;
    const float* p0 = part + (size_t)gi * CH * 20;
    float mmax = -INFINITY;
    for (int c = 0; c < CH; ++c) mmax = fmaxf(mmax, p0[c * 20]);
    float lsum = 0.f, wgt[4];
    for (int c = 0; c < CH; ++c) {
        wgt[c] = exp2f(p0[c * 20] - mmax);
        lsum += p0[c * 20 + 1] * wgt[c];
    }
    float inv = 1.f / lsum;
    const float4* Xr = (const float4*)(X + q * HID + h * HDIM);
    float4* Hr = (float4*)(H + q * HID + h * HDIM);
#pragma unroll
    for (int j = 0; j < 4; ++j) {
        float4 o = Xr[j];
        for (int c = 0; c < CH; ++c) {
            const float4 Av = *(const float4*)(p0 + c * 20 + 4 + 4 * j);
            float wc = wgt[c] * inv;
            o.x += Av.x * wc; o.y += Av.y * wc; o.z += Av.z * wc; o.w += Av.w * wc;
        }
        Hr[j] = o;
    }
}

// ---------------------------------------------------------------------------
// Fused mean-pool + MLP head. One block per batch. Batch arrays are sorted,
// so each block binary-searches its node ranges; zero atomics, no memset.
__global__ void k_poolfinal(const float* __restrict__ Hm, const float* __restrict__ Hp,
                            const int* __restrict__ mb, const int* __restrict__ pb,
                            const float* __restrict__ fc1W, const float* __restrict__ fc1b,
                            const float* __restrict__ fc2W, const float* __restrict__ fc2b,
                            float* __restrict__ out) {
    __shared__ float part[4][HID];
    __shared__ float z[2 * HID];
    int b = blockIdx.x;
    int t = threadIdx.x;
    int col = t & 63, w = t >> 6;
    // binary search segment boundaries (uniform across block)
    int ms, me, ps, pe;
    {
        int lo = 0, hi = N_MOL;
        while (lo < hi) { int mid = (lo + hi) >> 1; if (mb[mid] < b) lo = mid + 1; else hi = mid; }
        ms = lo; lo = ms; hi = N_MOL;
        while (lo < hi) { int mid = (lo + hi) >> 1; if (mb[mid] < b + 1) lo = mid + 1; else hi = mid; }
        me = lo;
        lo = 0; hi = N_PROT;
        while (lo < hi) { int mid = (lo + hi) >> 1; if (pb[mid] < b) lo = mid + 1; else hi = mid; }
        ps = lo; lo = ps; hi = N_PROT;
        while (lo < hi) { int mid = (lo + hi) >> 1; if (pb[mid] < b + 1) lo = mid + 1; else hi = mid; }
        pe = lo;
    }
    float s = 0.f;
    if (w < 2) {
        for (int r = ms + w; r < me; r += 2) s += Hm[r * HID + col];
    } else {
        for (int r = ps + (w - 2); r < pe; r += 2) s += Hp[r * HID + col];
    }
    part[w][col] = s;
    __syncthreads();
    if (w == 0) z[col] = (part[0][col] + part[1][col]) / fmaxf((float)(me - ms), 1.f);
    else if (w == 1) z[64 + col] = (part[2][col] + part[3][col]) / fmaxf((float)(pe - ps), 1.f);
    __syncthreads();
    if (t < 64) {
        float acc = fc1b[t];
        const float4* zv = (const float4*)z;
#pragma unroll
        for (int k = 0; k < 32; ++k) {
            float4 hv = zv[k];
            acc = fmaf(hv.x, fc1W[(4 * k + 0) * 64 + t], acc);
            acc = fmaf(hv.y, fc1W[(4 * k + 1) * 64 + t], acc);
            acc = fmaf(hv.z, fc1W[(4 * k + 2) * 64 + t], acc);
            acc = fmaf(hv.w, fc1W[(4 * k + 3) * 64 + t], acc);
        }
        float hv = fmaxf(acc, 0.f);
        float prod = hv * fc2W[t];
#pragma unroll
        for (int off = 32; off > 0; off >>= 1) prod += __shfl_xor(prod, off, 64);
        if (t == 0) out[b] = 1.f / (1.f + __expf(-(prod + fc2b[0])));
    }
}

// ---------------------------------------------------------------------------
extern "C" void kernel_launch(void* const* d_in, const int* in_sizes, int n_in,
                              void* d_out, int out_size, void* d_ws, size_t ws_size,
                              hipStream_t stream) {
    const float* mol_x   = (const float*)d_in[0];
    const float* prot_x  = (const float*)d_in[1];
    const float* mol_ea  = (const float*)d_in[2];
    const float* prot_ea = (const float*)d_in[3];
    const int*   mol_ei  = (const int*)d_in[4];
    const int*   prot_ei = (const int*)d_in[5];
    const int*   mol_b   = (const int*)d_in[6];
    const int*   prot_b  = (const int*)d_in[7];
    const float* nlmW = (const float*)d_in[8];
    const float* nlmb = (const float*)d_in[9];
    const float* nlpW = (const float*)d_in[10];
    const float* nlpb = (const float*)d_in[11];
    const float* elmW = (const float*)d_in[12];
    const float* elmb = (const float*)d_in[13];
    const float* elpW = (const float*)d_in[14];
    const float* elpb = (const float*)d_in[15];
    const float* mcW1 = (const float*)d_in[16];
    const float* mcb1 = (const float*)d_in[17];
    const float* mcW2 = (const float*)d_in[18];
    const float* mcb2 = (const float*)d_in[19];
    const float* pcW1 = (const float*)d_in[20];
    const float* pcb1 = (const float*)d_in[21];
    const float* pcW2 = (const float*)d_in[22];
    const float* pcb2 = (const float*)d_in[23];
    const float* mpW  = (const float*)d_in[24];
    const float* mpb  = (const float*)d_in[25];
    const float* pmW  = (const float*)d_in[26];
    const float* pmb  = (const float*)d_in[27];
    const float* fc1W = (const float*)d_in[28];
    const float* fc1b = (const float*)d_in[29];
    const float* fc2W = (const float*)d_in[30];
    const float* fc2b = (const float*)d_in[31];

    float* ws    = (float*)d_ws;
    float* xa_m  = ws;                  // 131072
    float* xa_p  = xa_m + 131072;       // 262144
    float* xb_m  = xa_p + 262144;       // 131072
    float* xb_p  = xb_m + 131072;       // 262144
    float* Qm    = xb_p + 262144;       // 131072
    float* Kp    = Qm + 131072;         // 262144
    float* Vp    = Kp + 262144;         // 262144
    float* Qp    = Vp + 262144;         // 262144
    float* Km    = Qp + 262144;         // 131072
    float* Vm    = Km + 131072;         // 131072
    float* partm = Vm + 131072;         // 2048*4*4*20 = 655360
    float* partp = partm + 655360;      // 4096*4*2*20 = 655360
    int* deg     = (int*)(partp + 655360);  // 6144
    int* rowptr  = deg + N_TOT;             // 6145
    int* cursor  = rowptr + N_TOT + 1;      // 6144
    int* eidx    = cursor + N_TOT;          // 163840
    // H reuses Q buffers (dead after k_attn)
    float* Hm = Qm;
    float* Hp = Qp;

    hipMemsetAsync(deg, 0, N_TOT * sizeof(int), stream);

    k_node_lin<<<N_TOT / 4, 256, 0, stream>>>(mol_x, prot_x, nlmW, nlmb, nlpW, nlpb, xa_m, xa_p);
    k_deg<<<E_TOT / 256, 256, 0, stream>>>(mol_ei, prot_ei, deg);
    k_scan<<<1, 256, 0, stream>>>(deg, rowptr, cursor);
    k_fill<<<E_TOT / 256, 256, 0, stream>>>(mol_ei, prot_ei, cursor, eidx);

    // 3 GINE layers, ping-pong xa <-> xb; final result lands in xb
    k_gine<<<N_TOT / 4, 256, 0, stream>>>(xa_m, xa_p, xb_m, xb_p, mol_ea, prot_ea, mol_ei, prot_ei,
        elmW, elmb, elpW, elpb,
        mcW1, mcb1, mcW2, mcb2, pcW1, pcb1, pcW2, pcb2, rowptr, eidx);
    k_gine<<<N_TOT / 4, 256, 0, stream>>>(xb_m, xb_p, xa_m, xa_p, mol_ea, prot_ea, mol_ei, prot_ei,
        elmW, elmb, elpW, elpb,
        mcW1 + 4096, mcb1 + 64, mcW2 + 4096, mcb2 + 64,
        pcW1 + 4096, pcb1 + 64, pcW2 + 4096, pcb2 + 64, rowptr, eidx);
    k_gine<<<N_TOT / 4, 256, 0, stream>>>(xa_m, xa_p, xb_m, xb_p, mol_ea, prot_ea, mol_ei, prot_ei,
        elmW, elmb, elpW, elpb,
        mcW1 + 8192, mcb1 + 128, mcW2 + 8192, mcb2 + 128,
        pcW1 + 8192, pcb1 + 128, pcW2 + 8192, pcb2 + 128, rowptr, eidx);

    k_qkv<<<18432 / 4, 256, 0, stream>>>(xb_m, xb_p, mpW, mpb, pmW, pmb, Qm, Kp, Vp, Qp, Km, Vm);
    k_attn<<<(N_MOL / TQA) * CH_MOL + (N_PROT / TQA) * CH_PROT, 256, 0, stream>>>(
        Qm, Kp, Vp, Qp, Km, Vm, partm, partp);
    k_attn_merge<<<(N_MOL + N_PROT) * HEADS / 256, 256, 0, stream>>>(
        partm, partp, xb_m, xb_p, Hm, Hp);

    k_poolfinal<<<BATCH, 256, 0, stream>>>(Hm, Hp, mol_b, prot_b,
                                           fc1W, fc1b, fc2W, fc2b, (float*)d_out);
}